// Round 5
// baseline (240.793 us; speedup 1.0000x reference)
//
#include <hip/hip_runtime.h>
#include <stdint.h>

// Binarized 3-layer CNN — bit-exact vs float32 reference (verified rounds 3/4).
// L1: f32 conv, strict sequential (kh,kw,c) per-pixel accumulation, 8 px/thread,
//     weights staged in LDS in t-order; stores p | (zero<<16) per pixel.
// L2: XOR+popcount fast path, 4 px/thread; exact ternary fallback (rare).
// L3: masked-popcount ternary conv, 4 px/thread.

#define H1 510
#define H2 508
#define H3 506
#define STRIDE 512

__global__ __launch_bounds__(256) void k_prep(const float* __restrict__ w1,
                                              const float* __restrict__ w2,
                                              const float* __restrict__ w3,
                                              float* __restrict__ lw,
                                              uint32_t* __restrict__ pw2,
                                              uint32_t* __restrict__ pw3) {
    int t = threadIdx.x;
    // sign(w1), reordered to [o][t=(r*3+j)*3+c], padded to 28/o
    for (int i = t; i < 448; i += 256) {
        int o = i / 28, k = i % 28;
        float v = 0.f;
        if (k < 27) {
            int c = k % 3, j = (k / 3) % 3, r = k / 9;
            float wv = w1[o * 27 + c * 9 + r * 3 + j];
            v = (wv > 0.f) ? 1.f : ((wv < 0.f) ? -1.f : 0.f);
        }
        lw[i] = v;
    }
    // w2 [23][16][3][3] -> per (o, tap-pair g): 16-bit channel masks, 2 taps/word
    for (int i = t; i < 23 * 5; i += 256) {
        int o = i / 5, g = i % 5;
        int k0 = 2 * g, k1 = 2 * g + 1;
        uint32_t lo = 0, hi = 0;
        for (int c = 0; c < 16; ++c) {
            if (w2[o * 144 + c * 9 + k0] > 0.f) lo |= 1u << c;
            if (k1 < 9 && w2[o * 144 + c * 9 + k1] > 0.f) hi |= 1u << c;
        }
        pw2[i] = lo | (hi << 16);
    }
    // w3 [2][23][3][3] -> per (o, tap k): 23-bit channel mask
    for (int i = t; i < 18; i += 256) {
        int o = i / 9, k = i % 9;
        uint32_t m = 0;
        for (int c = 0; c < 23; ++c)
            if (w3[o * 207 + c * 9 + k] > 0.f) m |= 1u << c;
        pw3[i] = m;
    }
}

// 8 output pixels per thread (4 wide x 2 tall); strict per-pixel (kh,kw,c) f32 order.
__global__ __launch_bounds__(256) void k_conv1(const float* __restrict__ in,
                                               const float* __restrict__ lw_g,
                                               uint32_t* __restrict__ t1) {
    __shared__ __align__(16) float lw[448];
    {
        int tid = threadIdx.y * 64 + threadIdx.x;
        for (int i = tid; i < 448; i += 256) lw[i] = lw_g[i];
    }
    __syncthreads();
    int gx = blockIdx.x * 64 + threadIdx.x;   // 0..127
    int hy = blockIdx.y * 4 + threadIdx.y;    // 0..255
    int b = blockIdx.z;
    int w0 = gx * 4;                          // 0..508
    int h0 = hy * 2;                          // 0..510
    if (h0 >= H1) return;                     // h0 <= 508 -> rows h0,h0+1 valid
    const float* base = in + (size_t)b * 3 * 512 * 512;
    float x[3][4][6];
    bool tail = (w0 + 4 >= 512);
#pragma unroll
    for (int c = 0; c < 3; ++c)
#pragma unroll
        for (int r = 0; r < 4; ++r) {
            const float* rp = base + c * 262144 + (size_t)(h0 + r) * 512 + w0;
            float4 v4 = *(const float4*)rp;
            x[c][r][0] = v4.x; x[c][r][1] = v4.y; x[c][r][2] = v4.z; x[c][r][3] = v4.w;
            if (!tail) {
                float2 v2 = *(const float2*)(rp + 4);
                x[c][r][4] = v2.x; x[c][r][5] = v2.y;
            } else {
                x[c][r][4] = 0.f; x[c][r][5] = 0.f;   // only feeds px cols 510/511 (unused)
            }
        }
    uint32_t res[8] = {0, 0, 0, 0, 0, 0, 0, 0};
#pragma unroll 1
    for (int o = 0; o < 16; ++o) {
        const float* wo = &lw[o * 28];
        float s[8];
#pragma unroll
        for (int p = 0; p < 8; ++p) s[p] = 0.f;
#pragma unroll
        for (int k = 0; k < 7; ++k) {
            float4 w4 = *(const float4*)&wo[k * 4];
            float wa[4] = {w4.x, w4.y, w4.z, w4.w};
#pragma unroll
            for (int i = 0; i < 4; ++i) {
                int t = k * 4 + i;                // ascending t = (r*3+j)*3+c
                if (t < 27) {
                    int c = t % 3, j = (t / 3) % 3, r = t / 9;
#pragma unroll
                    for (int pr = 0; pr < 2; ++pr)
#pragma unroll
                        for (int pc = 0; pc < 4; ++pc)
                            s[pr * 4 + pc] = fmaf(x[c][pr + r][pc + j], wa[i], s[pr * 4 + pc]);
                }
            }
        }
#pragma unroll
        for (int p = 0; p < 8; ++p)
            res[p] |= ((uint32_t)(s[p] > 0.f) << o) | ((uint32_t)(s[p] == 0.f) << (o + 16));
    }
    uint32_t* dst = t1 + (size_t)b * H1 * STRIDE;
#pragma unroll
    for (int pr = 0; pr < 2; ++pr)
        *(uint4*)(dst + (size_t)(h0 + pr) * STRIDE + w0) =
            make_uint4(res[pr * 4], res[pr * 4 + 1], res[pr * 4 + 2], res[pr * 4 + 3]);
}

// 4 px/thread. Fast path: all +-1 in the shared 3x6 window -> XOR+popcount.
__global__ __launch_bounds__(256) void k_conv2(const uint32_t* __restrict__ t1,
                                               const uint32_t* __restrict__ pw2,
                                               uint32_t* __restrict__ p2,
                                               uint32_t* __restrict__ m2) {
    int gx = blockIdx.x * 64 + threadIdx.x;   // 0..127
    int h = blockIdx.y * 4 + threadIdx.y;     // 0..507
    int b = blockIdx.z;
    int w0 = gx * 4;
    if (w0 >= H2 || h >= H2) return;          // w0 <= 504
    const uint32_t* base = t1 + (size_t)b * H1 * STRIDE;
    uint32_t A[3][6];
#pragma unroll
    for (int r = 0; r < 3; ++r) {
        const uint32_t* rp = base + (size_t)(h + r) * STRIDE + w0;
        uint4 q = *(const uint4*)rp;
        uint2 q2 = *(const uint2*)(rp + 4);
        A[r][0] = q.x; A[r][1] = q.y; A[r][2] = q.z; A[r][3] = q.w;
        A[r][4] = q2.x; A[r][5] = q2.y;
    }
    uint32_t orall = 0;
#pragma unroll
    for (int r = 0; r < 3; ++r)
#pragma unroll
        for (int j = 0; j < 6; ++j) orall |= A[r][j];
    uint32_t plus[4], minus[4];
    if ((orall >> 16) == 0) {
#pragma unroll
        for (int i = 0; i < 4; ++i) {
            uint32_t P0 = (A[0][i] & 0xFFFFu) | (A[0][i + 1] << 16);
            uint32_t P1 = (A[0][i + 2] & 0xFFFFu) | (A[1][i] << 16);
            uint32_t P2 = (A[1][i + 1] & 0xFFFFu) | (A[1][i + 2] << 16);
            uint32_t P3 = (A[2][i] & 0xFFFFu) | (A[2][i + 1] << 16);
            uint32_t P4 = (A[2][i + 2] & 0xFFFFu);
            uint32_t pl = 0, mi = 0;
#pragma unroll
            for (int o = 0; o < 23; ++o) {
                int cnt = __builtin_popcount(P0 ^ pw2[o * 5 + 0]) +
                          __builtin_popcount(P1 ^ pw2[o * 5 + 1]) +
                          __builtin_popcount(P2 ^ pw2[o * 5 + 2]) +
                          __builtin_popcount(P3 ^ pw2[o * 5 + 3]) +
                          __builtin_popcount(P4 ^ (pw2[o * 5 + 4] & 0xFFFFu));
                pl |= (((uint32_t)(cnt - 72)) >> 31) << o;
                mi |= (((uint32_t)(72 - cnt)) >> 31) << o;
            }
            plus[i] = pl; minus[i] = mi;
        }
    } else {
        // RARE: exact ternary path per pixel.
#pragma unroll
        for (int i = 0; i < 4; ++i) {
            uint32_t P[5], Z[5], M[5];
            P[0] = (A[0][i] & 0xFFFFu) | (A[0][i + 1] << 16);
            P[1] = (A[0][i + 2] & 0xFFFFu) | (A[1][i] << 16);
            P[2] = (A[1][i + 1] & 0xFFFFu) | (A[1][i + 2] << 16);
            P[3] = (A[2][i] & 0xFFFFu) | (A[2][i + 1] << 16);
            P[4] = (A[2][i + 2] & 0xFFFFu);
            Z[0] = (A[0][i] >> 16) | (A[0][i + 1] & 0xFFFF0000u);
            Z[1] = (A[0][i + 2] >> 16) | (A[1][i] & 0xFFFF0000u);
            Z[2] = (A[1][i + 1] >> 16) | (A[1][i + 2] & 0xFFFF0000u);
            Z[3] = (A[2][i] >> 16) | (A[2][i + 1] & 0xFFFF0000u);
            Z[4] = (A[2][i + 2] >> 16);
            M[0] = ~(P[0] | Z[0]);
            M[1] = ~(P[1] | Z[1]);
            M[2] = ~(P[2] | Z[2]);
            M[3] = ~(P[3] | Z[3]);
            M[4] = (~(P[4] | Z[4])) & 0xFFFFu;
            int sp = 0, sm = 0;
#pragma unroll
            for (int g = 0; g < 5; ++g) {
                sp += __builtin_popcount(P[g]);
                sm += __builtin_popcount(M[g]);
            }
            uint32_t pl = 0, mi = 0;
#pragma unroll
            for (int o = 0; o < 23; ++o) {
                int ap = 0, am = 0;
#pragma unroll
                for (int g = 0; g < 5; ++g) {
                    uint32_t W = pw2[o * 5 + g];
                    ap += __builtin_popcount(P[g] & W);
                    am += __builtin_popcount(M[g] & W);
                }
                int s = 2 * (ap - am) - sp + sm;
                pl |= (uint32_t)(s > 0) << o;
                mi |= (uint32_t)(s < 0) << o;
            }
            plus[i] = pl; minus[i] = mi;
        }
    }
    size_t idx = (size_t)b * H2 * STRIDE + (size_t)h * STRIDE + w0;
    *(uint4*)(p2 + idx) = make_uint4(plus[0], plus[1], plus[2], plus[3]);
    *(uint4*)(m2 + idx) = make_uint4(minus[0], minus[1], minus[2], minus[3]);
}

// 4 px/thread ternary conv -> f32
__global__ __launch_bounds__(256) void k_conv3(const uint32_t* __restrict__ p2,
                                               const uint32_t* __restrict__ m2,
                                               const uint32_t* __restrict__ pw3,
                                               float* __restrict__ out) {
    int gx = blockIdx.x * 64 + threadIdx.x;   // 0..127
    int h = blockIdx.y * 4 + threadIdx.y;     // 0..507
    int b = blockIdx.z;
    int w0 = gx * 4;
    if (w0 >= H2 || h >= H3) return;          // w0 <= 504, h <= 505
    const uint32_t* pb = p2 + (size_t)b * H2 * STRIDE;
    const uint32_t* mb = m2 + (size_t)b * H2 * STRIDE;
    uint32_t pp[3][6], mm[3][6];
#pragma unroll
    for (int r = 0; r < 3; ++r) {
        const uint32_t* rp = pb + (size_t)(h + r) * STRIDE + w0;
        uint4 q = *(const uint4*)rp;
        uint2 q2 = *(const uint2*)(rp + 4);
        pp[r][0] = q.x; pp[r][1] = q.y; pp[r][2] = q.z; pp[r][3] = q.w;
        pp[r][4] = q2.x; pp[r][5] = q2.y;
        const uint32_t* rm = mb + (size_t)(h + r) * STRIDE + w0;
        uint4 u = *(const uint4*)rm;
        uint2 u2 = *(const uint2*)(rm + 4);
        mm[r][0] = u.x; mm[r][1] = u.y; mm[r][2] = u.z; mm[r][3] = u.w;
        mm[r][4] = u2.x; mm[r][5] = u2.y;
    }
    float val[2][4];
#pragma unroll
    for (int i = 0; i < 4; ++i) {
        int Ps = 0, Ms = 0;
#pragma unroll
        for (int r = 0; r < 3; ++r)
#pragma unroll
            for (int j = 0; j < 3; ++j) {
                Ps += __builtin_popcount(pp[r][i + j]);
                Ms += __builtin_popcount(mm[r][i + j]);
            }
#pragma unroll
        for (int o = 0; o < 2; ++o) {
            int Ap = 0, Am = 0;
#pragma unroll
            for (int r = 0; r < 3; ++r)
#pragma unroll
                for (int j = 0; j < 3; ++j) {
                    uint32_t wm = pw3[o * 9 + r * 3 + j];
                    Ap += __builtin_popcount(pp[r][i + j] & wm);
                    Am += __builtin_popcount(mm[r][i + j] & wm);
                }
            int s = 2 * (Ap - Am) - Ps + Ms;
            val[o][i] = (s > 0) ? 1.f : ((s < 0) ? -1.f : 0.f);
        }
    }
#pragma unroll
    for (int o = 0; o < 2; ++o) {
        float* op = out + (size_t)b * (2 * H3 * H3) + (size_t)o * (H3 * H3) + (size_t)h * H3 + w0;
        *(float2*)op = make_float2(val[o][0], val[o][1]);
        if (w0 + 3 < H3)
            *(float2*)(op + 2) = make_float2(val[o][2], val[o][3]);
    }
}

extern "C" void kernel_launch(void* const* d_in, const int* in_sizes, int n_in,
                              void* d_out, int out_size, void* d_ws, size_t ws_size,
                              hipStream_t stream) {
    const float* inputs = (const float*)d_in[0];
    const float* w1 = (const float*)d_in[1];
    const float* w2 = (const float*)d_in[2];
    const float* w3 = (const float*)d_in[3];
    float* out = (float*)d_out;
    char* ws = (char*)d_ws;

    float* lw = (float*)(ws + 0);             // 448 f32 (reordered sign(w1))
    uint32_t* pw2 = (uint32_t*)(ws + 2048);   // 115 u32
    uint32_t* pw3 = (uint32_t*)(ws + 3072);   // 18 u32
    uint32_t* t1 = (uint32_t*)(ws + 4096);    // 32*510*512 u32 (L1: p | z<<16)
    size_t off_p2 = 4096 + (size_t)32 * H1 * STRIDE * 4;
    uint32_t* p2 = (uint32_t*)(ws + off_p2);  // 32*508*512 u32
    size_t off_m2 = off_p2 + (size_t)32 * H2 * STRIDE * 4;
    uint32_t* m2 = (uint32_t*)(ws + off_m2);
    size_t need = off_m2 + (size_t)32 * H2 * STRIDE * 4;
    if (ws_size < need) return;

    hipLaunchKernelGGL(k_prep, dim3(1), dim3(256), 0, stream, w1, w2, w3, lw, pw2, pw3);
    hipLaunchKernelGGL(k_conv1, dim3(2, 64, 32), dim3(64, 4), 0, stream, inputs, lw, t1);
    hipLaunchKernelGGL(k_conv2, dim3(2, 127, 32), dim3(64, 4), 0, stream, t1, pw2, p2, m2);
    hipLaunchKernelGGL(k_conv3, dim3(2, 127, 32), dim3(64, 4), 0, stream, p2, m2, pw3, out);
}

// Round 6
// 235.421 us; speedup vs baseline: 1.0228x; 1.0228x over previous
//
#include <hip/hip_runtime.h>
#include <stdint.h>

// Binarized 3-layer CNN — bit-exact vs float32 reference (verified r3-r5).
// L1: f32 conv, strict sequential (kh,kw,c) per-pixel order, 8 px/thread as
//     4 px-PAIRS via v_pk_fma_f32 (2 independent IEEE FMAs/instr -> order
//     per pixel unchanged). Weights duplicated {w,w} in LDS.
// L2: XOR+popcount, 1 px/thread, pw2 staged in LDS (no SGPR spill stalls);
//     exact two-plane ternary fallback for the ~never zero case.
// L3: masked-popcount ternary conv, 4 px/thread.

#define H1 510
#define H2 508
#define H3 506
#define STRIDE 512

typedef float f32x2 __attribute__((ext_vector_type(2)));

#define PKFMA(acc, x, w) \
    asm("v_pk_fma_f32 %0, %1, %2, %0" : "+v"(acc) : "v"(x), "v"(w))

__global__ __launch_bounds__(256) void k_prep(const float* __restrict__ w1,
                                              const float* __restrict__ w2,
                                              const float* __restrict__ w3,
                                              float* __restrict__ wdup,
                                              uint32_t* __restrict__ pw2,
                                              uint32_t* __restrict__ pw3) {
    int t = threadIdx.x;
    // sign(w1) duplicated {w,w}, order t=(r*3+j)*3+c (c fastest), padded 28/o
    for (int i = t; i < 448; i += 256) {
        int o = i / 28, k = i % 28;
        float v = 0.f;
        if (k < 27) {
            int c = k % 3, j = (k / 3) % 3, r = k / 9;
            float wv = w1[o * 27 + c * 9 + r * 3 + j];
            v = (wv > 0.f) ? 1.f : ((wv < 0.f) ? -1.f : 0.f);
        }
        wdup[2 * i] = v;
        wdup[2 * i + 1] = v;
    }
    // w2 [23][16][3][3] -> pw2[o*8+g]: 16-bit channel masks, 2 taps/word, g<5
    for (int i = t; i < 184; i += 256) {
        int o = i / 8, g = i % 8;
        uint32_t word = 0;
        if (g < 5) {
            int k0 = 2 * g, k1 = 2 * g + 1;
            for (int c = 0; c < 16; ++c) {
                if (w2[o * 144 + c * 9 + k0] > 0.f) word |= 1u << c;
                if (k1 < 9 && w2[o * 144 + c * 9 + k1] > 0.f) word |= 1u << (16 + c);
            }
            if (g == 4) word &= 0xFFFFu;
        }
        pw2[i] = word;
    }
    // w3 [2][23][3][3] -> per (o, tap k): 23-bit channel mask
    for (int i = t; i < 18; i += 256) {
        int o = i / 9, k = i % 9;
        uint32_t m = 0;
        for (int c = 0; c < 23; ++c)
            if (w3[o * 207 + c * 9 + k] > 0.f) m |= 1u << c;
        pw3[i] = m;
    }
}

// 8 px/thread (4 wide x 2 tall) as 4 pixel-pairs; v_pk_fma_f32 core.
__global__ __launch_bounds__(256) void k_conv1(const float* __restrict__ in,
                                               const float* __restrict__ wdup_g,
                                               uint32_t* __restrict__ t1) {
    __shared__ __align__(16) f32x2 wd[448];
    {
        int tid = threadIdx.y * 64 + threadIdx.x;
        const float* wg = wdup_g;
        float* wl = (float*)wd;
        for (int i = tid; i < 896; i += 256) wl[i] = wg[i];
    }
    __syncthreads();
    int gx = blockIdx.x * 64 + threadIdx.x;   // 0..127
    int hy = blockIdx.y * 4 + threadIdx.y;    // 0..255
    int b = blockIdx.z;
    int w0 = gx * 4;                          // 0..508
    int h0 = hy * 2;                          // 0..510
    if (h0 >= H1) return;
    const float* base = in + (size_t)b * 3 * 512 * 512;
    // Overlapping column pairs: xp[c][r][j] = {col j, col j+1}, j=0..4
    f32x2 xp[3][4][5];
    bool tail = (w0 + 4 >= 512);
#pragma unroll
    for (int c = 0; c < 3; ++c)
#pragma unroll
        for (int r = 0; r < 4; ++r) {
            const float* rp = base + c * 262144 + (size_t)(h0 + r) * 512 + w0;
            float4 v4 = *(const float4*)rp;
            float e4 = 0.f, e5 = 0.f;
            if (!tail) {
                float2 v2 = *(const float2*)(rp + 4);
                e4 = v2.x; e5 = v2.y;
            }
            xp[c][r][0] = f32x2{v4.x, v4.y};
            xp[c][r][1] = f32x2{v4.y, v4.z};
            xp[c][r][2] = f32x2{v4.z, v4.w};
            xp[c][r][3] = f32x2{v4.w, e4};
            xp[c][r][4] = f32x2{e4, e5};
        }
    uint32_t res[2][4] = {{0, 0, 0, 0}, {0, 0, 0, 0}};
#pragma unroll 1
    for (int o = 0; o < 16; ++o) {
        f32x2 a00 = f32x2{0.f, 0.f}, a01 = a00, a10 = a00, a11 = a00;
        const f32x2* wo = &wd[o * 28];
#pragma unroll
        for (int t = 0; t < 27; ++t) {        // ascending t = (r*3+j)*3+c
            f32x2 wp = wo[t];
            int c = t % 3, j = (t / 3) % 3, r = t / 9;
            PKFMA(a00, xp[c][r][j], wp);
            PKFMA(a01, xp[c][r][j + 2], wp);
            PKFMA(a10, xp[c][r + 1][j], wp);
            PKFMA(a11, xp[c][r + 1][j + 2], wp);
        }
        float sv[2][4] = {{a00.x, a00.y, a01.x, a01.y}, {a10.x, a10.y, a11.x, a11.y}};
#pragma unroll
        for (int pr = 0; pr < 2; ++pr)
#pragma unroll
            for (int pc = 0; pc < 4; ++pc) {
                uint32_t u = __float_as_uint(sv[pr][pc]);
                // s>0 <=> (int)u > 0 ; s==0 <=> u==0 (sum of +-x can't be -0)
                res[pr][pc] |= ((uint32_t)((int)u > 0) << o) |
                               ((uint32_t)(u == 0) << (o + 16));
            }
    }
    uint32_t* dst = t1 + (size_t)b * H1 * STRIDE;
#pragma unroll
    for (int pr = 0; pr < 2; ++pr)
        *(uint4*)(dst + (size_t)(h0 + pr) * STRIDE + w0) =
            make_uint4(res[pr][0], res[pr][1], res[pr][2], res[pr][3]);
}

// 1 px/thread; pw2 in LDS; XOR+popcount fast path, ternary fallback.
__global__ __launch_bounds__(256) void k_conv2(const uint32_t* __restrict__ t1,
                                               const uint32_t* __restrict__ pw2g,
                                               uint32_t* __restrict__ p2,
                                               uint32_t* __restrict__ m2) {
    __shared__ __align__(16) uint32_t wq[184];
    {
        int tid = threadIdx.y * 64 + threadIdx.x;
        for (int i = tid; i < 184; i += 256) wq[i] = pw2g[i];
    }
    __syncthreads();
    int w = blockIdx.x * 64 + threadIdx.x;
    int h = blockIdx.y * 4 + threadIdx.y;
    int b = blockIdx.z;
    if (w >= H2 || h >= H2) return;
    const uint32_t* base = t1 + (size_t)b * H1 * STRIDE;
    uint32_t A[9];
#pragma unroll
    for (int r = 0; r < 3; ++r)
#pragma unroll
        for (int j = 0; j < 3; ++j)
            A[r * 3 + j] = base[(size_t)(h + r) * STRIDE + (w + j)];
    uint32_t orall = A[0] | A[1] | A[2] | A[3] | A[4] | A[5] | A[6] | A[7] | A[8];
    uint32_t P[5];
    P[0] = (A[0] & 0xFFFFu) | (A[1] << 16);
    P[1] = (A[2] & 0xFFFFu) | (A[3] << 16);
    P[2] = (A[4] & 0xFFFFu) | (A[5] << 16);
    P[3] = (A[6] & 0xFFFFu) | (A[7] << 16);
    P[4] = (A[8] & 0xFFFFu);
    uint32_t plus = 0, minus = 0;
    if ((orall >> 16) == 0) {
        // FAST: all 144 activations +-1. s = 144 - 2*cnt.
#pragma unroll
        for (int o = 0; o < 23; ++o) {
            uint4 q = *(const uint4*)&wq[o * 8];
            uint32_t q4 = wq[o * 8 + 4];
            int cnt = __builtin_popcount(P[0] ^ q.x);
            cnt += __builtin_popcount(P[1] ^ q.y);
            cnt += __builtin_popcount(P[2] ^ q.z);
            cnt += __builtin_popcount(P[3] ^ q.w);
            cnt += __builtin_popcount(P[4] ^ q4);
            plus  |= (((uint32_t)(cnt - 72)) >> 31) << o;
            minus |= (((uint32_t)(72 - cnt)) >> 31) << o;
        }
    } else {
        // RARE: window contains an exact-zero L1 activation -> exact ternary.
        uint32_t Z[5], M[5];
        Z[0] = (A[0] >> 16) | (A[1] & 0xFFFF0000u);
        Z[1] = (A[2] >> 16) | (A[3] & 0xFFFF0000u);
        Z[2] = (A[4] >> 16) | (A[5] & 0xFFFF0000u);
        Z[3] = (A[6] >> 16) | (A[7] & 0xFFFF0000u);
        Z[4] = (A[8] >> 16);
        M[0] = ~(P[0] | Z[0]);
        M[1] = ~(P[1] | Z[1]);
        M[2] = ~(P[2] | Z[2]);
        M[3] = ~(P[3] | Z[3]);
        M[4] = (~(P[4] | Z[4])) & 0xFFFFu;
        int sp = 0, sm = 0;
#pragma unroll
        for (int g = 0; g < 5; ++g) {
            sp += __builtin_popcount(P[g]);
            sm += __builtin_popcount(M[g]);
        }
#pragma unroll
        for (int o = 0; o < 23; ++o) {
            int ap = 0, am = 0;
#pragma unroll
            for (int g = 0; g < 5; ++g) {
                uint32_t W = wq[o * 8 + g];
                ap += __builtin_popcount(P[g] & W);
                am += __builtin_popcount(M[g] & W);
            }
            int s = 2 * (ap - am) - sp + sm;
            plus  |= (uint32_t)(s > 0) << o;
            minus |= (uint32_t)(s < 0) << o;
        }
    }
    size_t idx = (size_t)b * H2 * STRIDE + (size_t)h * STRIDE + w;
    p2[idx] = plus;
    m2[idx] = minus;
}

// 4 px/thread ternary conv -> f32
__global__ __launch_bounds__(256) void k_conv3(const uint32_t* __restrict__ p2,
                                               const uint32_t* __restrict__ m2,
                                               const uint32_t* __restrict__ pw3,
                                               float* __restrict__ out) {
    int gx = blockIdx.x * 64 + threadIdx.x;   // 0..127
    int h = blockIdx.y * 4 + threadIdx.y;     // 0..507
    int b = blockIdx.z;
    int w0 = gx * 4;
    if (w0 >= H2 || h >= H3) return;
    const uint32_t* pb = p2 + (size_t)b * H2 * STRIDE;
    const uint32_t* mb = m2 + (size_t)b * H2 * STRIDE;
    uint32_t pp[3][6], mm[3][6];
#pragma unroll
    for (int r = 0; r < 3; ++r) {
        const uint32_t* rp = pb + (size_t)(h + r) * STRIDE + w0;
        uint4 q = *(const uint4*)rp;
        uint2 q2 = *(const uint2*)(rp + 4);
        pp[r][0] = q.x; pp[r][1] = q.y; pp[r][2] = q.z; pp[r][3] = q.w;
        pp[r][4] = q2.x; pp[r][5] = q2.y;
        const uint32_t* rm = mb + (size_t)(h + r) * STRIDE + w0;
        uint4 u = *(const uint4*)rm;
        uint2 u2 = *(const uint2*)(rm + 4);
        mm[r][0] = u.x; mm[r][1] = u.y; mm[r][2] = u.z; mm[r][3] = u.w;
        mm[r][4] = u2.x; mm[r][5] = u2.y;
    }
    float val[2][4];
#pragma unroll
    for (int i = 0; i < 4; ++i) {
        int Ps = 0, Ms = 0;
#pragma unroll
        for (int r = 0; r < 3; ++r)
#pragma unroll
            for (int j = 0; j < 3; ++j) {
                Ps += __builtin_popcount(pp[r][i + j]);
                Ms += __builtin_popcount(mm[r][i + j]);
            }
#pragma unroll
        for (int o = 0; o < 2; ++o) {
            int Ap = 0, Am = 0;
#pragma unroll
            for (int r = 0; r < 3; ++r)
#pragma unroll
                for (int j = 0; j < 3; ++j) {
                    uint32_t wm = pw3[o * 9 + r * 3 + j];
                    Ap += __builtin_popcount(pp[r][i + j] & wm);
                    Am += __builtin_popcount(mm[r][i + j] & wm);
                }
            int s = 2 * (Ap - Am) - Ps + Ms;
            val[o][i] = (s > 0) ? 1.f : ((s < 0) ? -1.f : 0.f);
        }
    }
#pragma unroll
    for (int o = 0; o < 2; ++o) {
        float* op = out + (size_t)b * (2 * H3 * H3) + (size_t)o * (H3 * H3) + (size_t)h * H3 + w0;
        *(float2*)op = make_float2(val[o][0], val[o][1]);
        if (w0 + 3 < H3)
            *(float2*)(op + 2) = make_float2(val[o][2], val[o][3]);
    }
}

extern "C" void kernel_launch(void* const* d_in, const int* in_sizes, int n_in,
                              void* d_out, int out_size, void* d_ws, size_t ws_size,
                              hipStream_t stream) {
    const float* inputs = (const float*)d_in[0];
    const float* w1 = (const float*)d_in[1];
    const float* w2 = (const float*)d_in[2];
    const float* w3 = (const float*)d_in[3];
    float* out = (float*)d_out;
    char* ws = (char*)d_ws;

    float* wdup = (float*)(ws + 0);           // 896 f32 ({w,w} pairs)
    uint32_t* pw2 = (uint32_t*)(ws + 4096);   // 184 u32 (stride 8/o)
    uint32_t* pw3 = (uint32_t*)(ws + 5120);   // 18 u32
    uint32_t* t1 = (uint32_t*)(ws + 8192);    // 32*510*512 u32 (L1: p | z<<16)
    size_t off_p2 = 8192 + (size_t)32 * H1 * STRIDE * 4;
    uint32_t* p2 = (uint32_t*)(ws + off_p2);  // 32*508*512 u32
    size_t off_m2 = off_p2 + (size_t)32 * H2 * STRIDE * 4;
    uint32_t* m2 = (uint32_t*)(ws + off_m2);
    size_t need = off_m2 + (size_t)32 * H2 * STRIDE * 4;
    if (ws_size < need) return;

    hipLaunchKernelGGL(k_prep, dim3(1), dim3(256), 0, stream, w1, w2, w3, wdup, pw2, pw3);
    hipLaunchKernelGGL(k_conv1, dim3(2, 64, 32), dim3(64, 4), 0, stream, inputs, wdup, t1);
    hipLaunchKernelGGL(k_conv2, dim3(8, 127, 32), dim3(64, 4), 0, stream, t1, pw2, p2, m2);
    hipLaunchKernelGGL(k_conv3, dim3(2, 127, 32), dim3(64, 4), 0, stream, p2, m2, pw3, out);
}

// Round 7
// 230.222 us; speedup vs baseline: 1.0459x; 1.0226x over previous
//
#include <hip/hip_runtime.h>
#include <stdint.h>

// Binarized 3-layer CNN — bit-exact vs float32 reference (verified r3-r6).
// L1: f32 conv, strict sequential (kh,kw,c) per-pixel order, 8 px/thread,
//     weights (t-order) in LDS, scalar v_fma. Output per px: n-plane (sign bit)
//     lo16 | z-plane (exact-zero) hi16, built with funnel-shift chains (o desc).
// L2: XOR+popcount with NEGATIVE weight masks: cnt=popc(n^m), d=cnt-72 via
//     bcnt accumulate; plus/minus masks via funnel shifts. Exact ternary
//     fallback for windows containing a zero (~never).
// L3: masked-popcount ternary conv, 4 px/thread.

#define H1 510
#define H2 508
#define H3 506
#define STRIDE 512

__global__ __launch_bounds__(256) void k_prep(const float* __restrict__ w1,
                                              const float* __restrict__ w2,
                                              const float* __restrict__ w3,
                                              float* __restrict__ lw,
                                              uint32_t* __restrict__ pw2,
                                              uint32_t* __restrict__ pw3) {
    int t = threadIdx.x;
    // sign(w1), order t=(r*3+j)*3+c (c fastest), padded to 28/o
    for (int i = t; i < 448; i += 256) {
        int o = i / 28, k = i % 28;
        float v = 0.f;
        if (k < 27) {
            int c = k % 3, j = (k / 3) % 3, r = k / 9;
            float wv = w1[o * 27 + c * 9 + r * 3 + j];
            v = (wv > 0.f) ? 1.f : ((wv < 0.f) ? -1.f : 0.f);
        }
        lw[i] = v;
    }
    // w2 [23][16][3][3] -> pw2[o*8+g]: NEGATIVE-mask 16-bit channel words,
    // 2 taps/word (k0 lo16, k1 hi16), g<5; g==4 hi16 = 0.
    for (int i = t; i < 184; i += 256) {
        int o = i / 8, g = i % 8;
        uint32_t word = 0;
        if (g < 5) {
            int k0 = 2 * g, k1 = 2 * g + 1;
            for (int c = 0; c < 16; ++c) {
                if (!(w2[o * 144 + c * 9 + k0] > 0.f)) word |= 1u << c;
                if (k1 < 9 && !(w2[o * 144 + c * 9 + k1] > 0.f)) word |= 1u << (16 + c);
            }
        }
        pw2[i] = word;
    }
    // w3 [2][23][3][3] -> per (o, tap k): POSITIVE 23-bit channel mask
    for (int i = t; i < 18; i += 256) {
        int o = i / 9, k = i % 9;
        uint32_t m = 0;
        for (int c = 0; c < 23; ++c)
            if (w3[o * 207 + c * 9 + k] > 0.f) m |= 1u << c;
        pw3[i] = m;
    }
}

// 8 px/thread (4 wide x 2 tall); strict per-pixel (kh,kw,c) f32 order.
__global__ __launch_bounds__(256) void k_conv1(const float* __restrict__ in,
                                               const float* __restrict__ lw_g,
                                               uint32_t* __restrict__ t1) {
    __shared__ __align__(16) float lw[448];
    {
        int tid = threadIdx.y * 64 + threadIdx.x;
        for (int i = tid; i < 448; i += 256) lw[i] = lw_g[i];
    }
    __syncthreads();
    int gx = blockIdx.x * 64 + threadIdx.x;   // 0..127
    int hy = blockIdx.y * 4 + threadIdx.y;    // 0..255
    int b = blockIdx.z;
    int w0 = gx * 4;                          // 0..508
    int h0 = hy * 2;                          // 0..510
    if (h0 >= H1) return;
    const float* base = in + (size_t)b * 3 * 512 * 512;
    float x[3][4][6];
    bool tail = (w0 + 4 >= 512);
#pragma unroll
    for (int c = 0; c < 3; ++c)
#pragma unroll
        for (int r = 0; r < 4; ++r) {
            const float* rp = base + c * 262144 + (size_t)(h0 + r) * 512 + w0;
            float4 v4 = *(const float4*)rp;
            x[c][r][0] = v4.x; x[c][r][1] = v4.y; x[c][r][2] = v4.z; x[c][r][3] = v4.w;
            if (!tail) {
                float2 v2 = *(const float2*)(rp + 4);
                x[c][r][4] = v2.x; x[c][r][5] = v2.y;
            } else {
                x[c][r][4] = 0.f; x[c][r][5] = 0.f;   // feeds only px >= H1 (unread)
            }
        }
    uint32_t rn[8] = {0, 0, 0, 0, 0, 0, 0, 0};   // sign-bit planes (funnel chains)
    uint32_t rz[8] = {0, 0, 0, 0, 0, 0, 0, 0};   // NONZERO-bit planes
#pragma unroll 1
    for (int o = 15; o >= 0; --o) {              // o order irrelevant to rounding
        const float* wo = &lw[o * 28];
        float s[8];
#pragma unroll
        for (int p = 0; p < 8; ++p) s[p] = 0.f;
#pragma unroll
        for (int k = 0; k < 7; ++k) {
            float4 w4 = *(const float4*)&wo[k * 4];
            float wa[4] = {w4.x, w4.y, w4.z, w4.w};
#pragma unroll
            for (int i = 0; i < 4; ++i) {
                int t = k * 4 + i;                // ascending t = (r*3+j)*3+c
                if (t < 27) {
                    int c = t % 3, j = (t / 3) % 3, r = t / 9;
#pragma unroll
                    for (int pr = 0; pr < 2; ++pr)
#pragma unroll
                        for (int pc = 0; pc < 4; ++pc)
                            s[pr * 4 + pc] = fmaf(x[c][pr + r][pc + j], wa[i], s[pr * 4 + pc]);
                }
            }
        }
#pragma unroll
        for (int p = 0; p < 8; ++p) {
            uint32_t u = __float_as_uint(s[p]);
            rn[p] = (rn[p] << 1) | (u >> 31);            // v_alignbit
            uint32_t nz = u | (0u - u);                  // sign = (u != 0)
            rz[p] = (rz[p] << 1) | (nz >> 31);
        }
    }
    uint32_t* dst = t1 + (size_t)b * H1 * STRIDE;
#pragma unroll
    for (int pr = 0; pr < 2; ++pr) {
        uint32_t w4[4];
#pragma unroll
        for (int pc = 0; pc < 4; ++pc)
            w4[pc] = rn[pr * 4 + pc] | (~rz[pr * 4 + pc] << 16);  // n lo16 | z hi16
        *(uint4*)(dst + (size_t)(h0 + pr) * STRIDE + w0) =
            make_uint4(w4[0], w4[1], w4[2], w4[3]);
    }
}

// 1 px/thread; pw2 (neg masks) in LDS; XOR+popcount fast path, ternary fallback.
__global__ __launch_bounds__(256) void k_conv2(const uint32_t* __restrict__ t1,
                                               const uint32_t* __restrict__ pw2g,
                                               uint32_t* __restrict__ p2,
                                               uint32_t* __restrict__ m2) {
    __shared__ __align__(16) uint32_t wq[184];
    {
        int tid = threadIdx.y * 64 + threadIdx.x;
        for (int i = tid; i < 184; i += 256) wq[i] = pw2g[i];
    }
    __syncthreads();
    int w = blockIdx.x * 64 + threadIdx.x;
    int h = blockIdx.y * 4 + threadIdx.y;
    int b = blockIdx.z;
    if (w >= H2 || h >= H2) return;
    const uint32_t* base = t1 + (size_t)b * H1 * STRIDE;
    uint32_t A[9];
#pragma unroll
    for (int r = 0; r < 3; ++r)
#pragma unroll
        for (int j = 0; j < 3; ++j)
            A[r * 3 + j] = base[(size_t)(h + r) * STRIDE + (w + j)];
    uint32_t orall = A[0] | A[1] | A[2] | A[3] | A[4] | A[5] | A[6] | A[7] | A[8];
    // n-plane packed 2 taps/word
    uint32_t N0 = (A[0] & 0xFFFFu) | (A[1] << 16);
    uint32_t N1 = (A[2] & 0xFFFFu) | (A[3] << 16);
    uint32_t N2 = (A[4] & 0xFFFFu) | (A[5] << 16);
    uint32_t N3 = (A[6] & 0xFFFFu) | (A[7] << 16);
    uint32_t N4 = (A[8] & 0xFFFFu);
    uint32_t plus = 0, minus = 0;
    if ((orall >> 16) == 0) {
        // FAST: all 144 activations +-1. cnt_neg = popc(n^m); d = cnt-72.
#pragma unroll
        for (int o = 22; o >= 0; --o) {
            uint4 q = *(const uint4*)&wq[o * 8];
            uint32_t q4 = wq[o * 8 + 4];
            int d = __builtin_popcount(N0 ^ q.x) + __builtin_popcount(N1 ^ q.y) +
                    __builtin_popcount(N2 ^ q.z) + __builtin_popcount(N3 ^ q.w) +
                    __builtin_popcount(N4 ^ q4) - 72;
            plus  = (plus << 1)  | (((uint32_t)d) >> 31);        // d<0 -> s>0
            minus = (minus << 1) | (((uint32_t)(0 - d)) >> 31);  // d>0 -> s<0
        }
    } else {
        // RARE: window contains an exact-zero L1 activation -> exact ternary.
        uint32_t P[5], M[5];
        {
            uint32_t p16[9], m16[9];
#pragma unroll
            for (int k = 0; k < 9; ++k) {
                uint32_t z = A[k] >> 16;
                p16[k] = (~(A[k] | z)) & 0xFFFFu;   // +1: !n && !z
                m16[k] = (A[k] & ~z) & 0xFFFFu;     // -1: n && !z
            }
            P[0] = p16[0] | (p16[1] << 16); M[0] = m16[0] | (m16[1] << 16);
            P[1] = p16[2] | (p16[3] << 16); M[1] = m16[2] | (m16[3] << 16);
            P[2] = p16[4] | (p16[5] << 16); M[2] = m16[4] | (m16[5] << 16);
            P[3] = p16[6] | (p16[7] << 16); M[3] = m16[6] | (m16[7] << 16);
            P[4] = p16[8];                  M[4] = m16[8];
        }
        int sp = 0, sm = 0;
#pragma unroll
        for (int g = 0; g < 5; ++g) {
            sp += __builtin_popcount(P[g]);
            sm += __builtin_popcount(M[g]);
        }
#pragma unroll
        for (int o = 0; o < 23; ++o) {
            int ap = 0, am = 0;
#pragma unroll
            for (int g = 0; g < 5; ++g) {
                uint32_t Wn = wq[o * 8 + g];    // negative mask
                ap += __builtin_popcount(P[g] & Wn);
                am += __builtin_popcount(M[g] & Wn);
            }
            // s = (sp - sm) + 2*(am - ap)   [derived from pos = ~neg]
            int s = sp - sm + 2 * (am - ap);
            plus  |= (uint32_t)(s > 0) << o;
            minus |= (uint32_t)(s < 0) << o;
        }
    }
    size_t idx = (size_t)b * H2 * STRIDE + (size_t)h * STRIDE + w;
    p2[idx] = plus;
    m2[idx] = minus;
}

// 4 px/thread ternary conv -> f32
__global__ __launch_bounds__(256) void k_conv3(const uint32_t* __restrict__ p2,
                                               const uint32_t* __restrict__ m2,
                                               const uint32_t* __restrict__ pw3,
                                               float* __restrict__ out) {
    int gx = blockIdx.x * 64 + threadIdx.x;   // 0..127
    int h = blockIdx.y * 4 + threadIdx.y;     // 0..507
    int b = blockIdx.z;
    int w0 = gx * 4;
    if (w0 >= H2 || h >= H3) return;
    const uint32_t* pb = p2 + (size_t)b * H2 * STRIDE;
    const uint32_t* mb = m2 + (size_t)b * H2 * STRIDE;
    uint32_t pp[3][6], mm[3][6];
#pragma unroll
    for (int r = 0; r < 3; ++r) {
        const uint32_t* rp = pb + (size_t)(h + r) * STRIDE + w0;
        uint4 q = *(const uint4*)rp;
        uint2 q2 = *(const uint2*)(rp + 4);
        pp[r][0] = q.x; pp[r][1] = q.y; pp[r][2] = q.z; pp[r][3] = q.w;
        pp[r][4] = q2.x; pp[r][5] = q2.y;
        const uint32_t* rm = mb + (size_t)(h + r) * STRIDE + w0;
        uint4 u = *(const uint4*)rm;
        uint2 u2 = *(const uint2*)(rm + 4);
        mm[r][0] = u.x; mm[r][1] = u.y; mm[r][2] = u.z; mm[r][3] = u.w;
        mm[r][4] = u2.x; mm[r][5] = u2.y;
    }
    float val[2][4];
#pragma unroll
    for (int i = 0; i < 4; ++i) {
        int Ps = 0, Ms = 0;
#pragma unroll
        for (int r = 0; r < 3; ++r)
#pragma unroll
            for (int j = 0; j < 3; ++j) {
                Ps += __builtin_popcount(pp[r][i + j]);
                Ms += __builtin_popcount(mm[r][i + j]);
            }
#pragma unroll
        for (int o = 0; o < 2; ++o) {
            int Ap = 0, Am = 0;
#pragma unroll
            for (int r = 0; r < 3; ++r)
#pragma unroll
                for (int j = 0; j < 3; ++j) {
                    uint32_t wm = pw3[o * 9 + r * 3 + j];
                    Ap += __builtin_popcount(pp[r][i + j] & wm);
                    Am += __builtin_popcount(mm[r][i + j] & wm);
                }
            int s = 2 * (Ap - Am) - Ps + Ms;
            val[o][i] = (s > 0) ? 1.f : ((s < 0) ? -1.f : 0.f);
        }
    }
#pragma unroll
    for (int o = 0; o < 2; ++o) {
        float* op = out + (size_t)b * (2 * H3 * H3) + (size_t)o * (H3 * H3) + (size_t)h * H3 + w0;
        *(float2*)op = make_float2(val[o][0], val[o][1]);
        if (w0 + 3 < H3)
            *(float2*)(op + 2) = make_float2(val[o][2], val[o][3]);
    }
}

extern "C" void kernel_launch(void* const* d_in, const int* in_sizes, int n_in,
                              void* d_out, int out_size, void* d_ws, size_t ws_size,
                              hipStream_t stream) {
    const float* inputs = (const float*)d_in[0];
    const float* w1 = (const float*)d_in[1];
    const float* w2 = (const float*)d_in[2];
    const float* w3 = (const float*)d_in[3];
    float* out = (float*)d_out;
    char* ws = (char*)d_ws;

    float* lw = (float*)(ws + 0);             // 448 f32 (reordered sign(w1))
    uint32_t* pw2 = (uint32_t*)(ws + 2048);   // 184 u32 (neg masks, stride 8/o)
    uint32_t* pw3 = (uint32_t*)(ws + 4096);   // 18 u32
    uint32_t* t1 = (uint32_t*)(ws + 8192);    // 32*510*512 u32 (L1: n | z<<16)
    size_t off_p2 = 8192 + (size_t)32 * H1 * STRIDE * 4;
    uint32_t* p2 = (uint32_t*)(ws + off_p2);  // 32*508*512 u32
    size_t off_m2 = off_p2 + (size_t)32 * H2 * STRIDE * 4;
    uint32_t* m2 = (uint32_t*)(ws + off_m2);
    size_t need = off_m2 + (size_t)32 * H2 * STRIDE * 4;
    if (ws_size < need) return;

    hipLaunchKernelGGL(k_prep, dim3(1), dim3(256), 0, stream, w1, w2, w3, lw, pw2, pw3);
    hipLaunchKernelGGL(k_conv1, dim3(2, 64, 32), dim3(64, 4), 0, stream, inputs, lw, t1);
    hipLaunchKernelGGL(k_conv2, dim3(8, 127, 32), dim3(64, 4), 0, stream, t1, pw2, p2, m2);
    hipLaunchKernelGGL(k_conv3, dim3(2, 127, 32), dim3(64, 4), 0, stream, p2, m2, pw3, out);
}

// Round 8
// 198.038 us; speedup vs baseline: 1.2159x; 1.1625x over previous
//
#include <hip/hip_runtime.h>
#include <stdint.h>

// Binarized 3-layer CNN — bit-exact vs float32 reference (verified r3-r7).
// L1: f32 conv, strict sequential (kh,kw,c) per-pixel order, 8 px/thread,
//     weights read via wave-uniform s_load (no LDS). Output: n-plane lo16 |
//     z-plane hi16 via funnel chains.
// L2: XOR+popcount vs NEGATIVE weight masks; v_perm packing, inline-asm
//     v_bcnt accumulate chains (init -72) + v_alignbit funnels. Exact ternary
//     fallback for windows containing an exact-zero (~never taken).
// L3: masked-popcount ternary conv, 4 px/thread, asm bcnt chains.

#define H1 510
#define H2 508
#define H3 506
#define STRIDE 512

#define BCNT_ACC(acc, x) \
    asm("v_bcnt_u32_b32 %0, %1, %0" : "+v"(acc) : "v"(x))
#define FUNNEL31(word, val) \
    asm("v_alignbit_b32 %0, %0, %1, 31" : "+v"(word) : "v"(val))

__global__ __launch_bounds__(256) void k_prep(const float* __restrict__ w1,
                                              const float* __restrict__ w2,
                                              const float* __restrict__ w3,
                                              float* __restrict__ lw,
                                              uint32_t* __restrict__ pw2,
                                              uint32_t* __restrict__ pw3) {
    int t = threadIdx.x;
    // sign(w1), order t=(r*3+j)*3+c (c fastest), padded to 28/o
    for (int i = t; i < 448; i += 256) {
        int o = i / 28, k = i % 28;
        float v = 0.f;
        if (k < 27) {
            int c = k % 3, j = (k / 3) % 3, r = k / 9;
            float wv = w1[o * 27 + c * 9 + r * 3 + j];
            v = (wv > 0.f) ? 1.f : ((wv < 0.f) ? -1.f : 0.f);
        }
        lw[i] = v;
    }
    // w2 [23][16][3][3] -> pw2[o*8+g]: NEGATIVE-mask 16-bit channel words,
    // 2 taps/word (k0 lo16, k1 hi16), g<5; g==4 hi16 = 0.
    for (int i = t; i < 184; i += 256) {
        int o = i / 8, g = i % 8;
        uint32_t word = 0;
        if (g < 5) {
            int k0 = 2 * g, k1 = 2 * g + 1;
            for (int c = 0; c < 16; ++c) {
                if (!(w2[o * 144 + c * 9 + k0] > 0.f)) word |= 1u << c;
                if (k1 < 9 && !(w2[o * 144 + c * 9 + k1] > 0.f)) word |= 1u << (16 + c);
            }
        }
        pw2[i] = word;
    }
    // w3 [2][23][3][3] -> per (o, tap k): POSITIVE 23-bit channel mask
    for (int i = t; i < 18; i += 256) {
        int o = i / 9, k = i % 9;
        uint32_t m = 0;
        for (int c = 0; c < 23; ++c)
            if (w3[o * 207 + c * 9 + k] > 0.f) m |= 1u << c;
        pw3[i] = m;
    }
}

// 8 px/thread (4 wide x 2 tall); strict per-pixel (kh,kw,c) f32 order.
// Weights via wave-uniform global reads -> scalar loads on the SMEM pipe.
__global__ __launch_bounds__(256) void k_conv1(const float* __restrict__ in,
                                               const float* __restrict__ lw_g,
                                               uint32_t* __restrict__ t1) {
    int gx = blockIdx.x * 64 + threadIdx.x;   // 0..127
    int hy = blockIdx.y * 4 + threadIdx.y;    // 0..255
    int b = blockIdx.z;
    int w0 = gx * 4;                          // 0..508
    int h0 = hy * 2;                          // 0..510
    if (h0 >= H1) return;
    const float* base = in + (size_t)b * 3 * 512 * 512;
    float x[3][4][6];
    bool tail = (w0 + 4 >= 512);
#pragma unroll
    for (int c = 0; c < 3; ++c)
#pragma unroll
        for (int r = 0; r < 4; ++r) {
            const float* rp = base + c * 262144 + (size_t)(h0 + r) * 512 + w0;
            float4 v4 = *(const float4*)rp;
            x[c][r][0] = v4.x; x[c][r][1] = v4.y; x[c][r][2] = v4.z; x[c][r][3] = v4.w;
            if (!tail) {
                float2 v2 = *(const float2*)(rp + 4);
                x[c][r][4] = v2.x; x[c][r][5] = v2.y;
            } else {
                x[c][r][4] = 0.f; x[c][r][5] = 0.f;   // feeds only px >= H1 (unread)
            }
        }
    uint32_t rn[8] = {0, 0, 0, 0, 0, 0, 0, 0};   // sign-bit planes
    uint32_t rz[8] = {0, 0, 0, 0, 0, 0, 0, 0};   // NONZERO-bit planes
#pragma unroll 1
    for (int o = 15; o >= 0; --o) {              // o order irrelevant to rounding
        const float* wo = lw_g + o * 28;         // uniform address -> s_load
        float s[8];
#pragma unroll
        for (int p = 0; p < 8; ++p) s[p] = 0.f;
#pragma unroll
        for (int t = 0; t < 27; ++t) {           // ascending t = (r*3+j)*3+c
            float wv = wo[t];
            int c = t % 3, j = (t / 3) % 3, r = t / 9;
#pragma unroll
            for (int pr = 0; pr < 2; ++pr)
#pragma unroll
                for (int pc = 0; pc < 4; ++pc)
                    s[pr * 4 + pc] = fmaf(x[c][pr + r][pc + j], wv, s[pr * 4 + pc]);
        }
#pragma unroll
        for (int p = 0; p < 8; ++p) {
            uint32_t u = __float_as_uint(s[p]);
            rn[p] = (rn[p] << 1) | (u >> 31);
            uint32_t nz = u | (0u - u);          // sign set iff u != 0
            rz[p] = (rz[p] << 1) | (nz >> 31);
        }
    }
    uint32_t* dst = t1 + (size_t)b * H1 * STRIDE;
#pragma unroll
    for (int pr = 0; pr < 2; ++pr) {
        uint32_t w4[4];
#pragma unroll
        for (int pc = 0; pc < 4; ++pc)
            w4[pc] = rn[pr * 4 + pc] | (~rz[pr * 4 + pc] << 16);  // n lo16 | z hi16
        *(uint4*)(dst + (size_t)(h0 + pr) * STRIDE + w0) =
            make_uint4(w4[0], w4[1], w4[2], w4[3]);
    }
}

// 1 px/thread; pw2 (neg masks) in LDS; asm bcnt/alignbit core.
__global__ __launch_bounds__(256) void k_conv2(const uint32_t* __restrict__ t1,
                                               const uint32_t* __restrict__ pw2g,
                                               uint32_t* __restrict__ p2,
                                               uint32_t* __restrict__ m2) {
    __shared__ __align__(16) uint32_t wq[184];
    {
        int tid = threadIdx.y * 64 + threadIdx.x;
        for (int i = tid; i < 184; i += 256) wq[i] = pw2g[i];
    }
    __syncthreads();
    int w = blockIdx.x * 64 + threadIdx.x;
    int h = blockIdx.y * 4 + threadIdx.y;
    int b = blockIdx.z;
    if (w >= H2 || h >= H2) return;
    const uint32_t* base = t1 + (size_t)b * H1 * STRIDE;
    uint32_t A[9];
#pragma unroll
    for (int r = 0; r < 3; ++r)
#pragma unroll
        for (int j = 0; j < 3; ++j)
            A[r * 3 + j] = base[(size_t)(h + r) * STRIDE + (w + j)];
    uint32_t orall = A[0] | A[1] | A[2] | A[3] | A[4] | A[5] | A[6] | A[7] | A[8];
    // n-plane, 2 taps/word via byte-perm: dst = lo16(b) | lo16(a)<<16
    uint32_t N0 = __builtin_amdgcn_perm(A[1], A[0], 0x05040100u);
    uint32_t N1 = __builtin_amdgcn_perm(A[3], A[2], 0x05040100u);
    uint32_t N2 = __builtin_amdgcn_perm(A[5], A[4], 0x05040100u);
    uint32_t N3 = __builtin_amdgcn_perm(A[7], A[6], 0x05040100u);
    uint32_t N4 = A[8] & 0xFFFFu;
    uint32_t plus = 0, minus = 0;
    if ((orall >> 16) == 0) {
        // FAST: all 144 activations +-1. d = popc_mismatch - 72; bit o desc.
#pragma unroll
        for (int o = 22; o >= 0; --o) {
            uint4 q = *(const uint4*)&wq[o * 8];
            uint32_t q4 = wq[o * 8 + 4];
            uint32_t t0 = N0 ^ q.x, t1x = N1 ^ q.y, t2 = N2 ^ q.z,
                     t3 = N3 ^ q.w, t4 = N4 ^ q4;
            int cnt = -72;
            BCNT_ACC(cnt, t0);
            BCNT_ACC(cnt, t1x);
            BCNT_ACC(cnt, t2);
            BCNT_ACC(cnt, t3);
            BCNT_ACC(cnt, t4);
            int nd = -cnt;
            FUNNEL31(plus, cnt);     // bit = (cnt<0)  -> s>0
            FUNNEL31(minus, nd);     // bit = (cnt>0)  -> s<0
        }
    } else {
        // RARE: window contains an exact-zero L1 activation -> exact ternary.
        uint32_t P[5], M[5];
        {
            uint32_t p16[9], m16[9];
#pragma unroll
            for (int k = 0; k < 9; ++k) {
                uint32_t z = A[k] >> 16;
                p16[k] = (~(A[k] | z)) & 0xFFFFu;   // +1: !n && !z
                m16[k] = (A[k] & ~z) & 0xFFFFu;     // -1: n && !z
            }
            P[0] = p16[0] | (p16[1] << 16); M[0] = m16[0] | (m16[1] << 16);
            P[1] = p16[2] | (p16[3] << 16); M[1] = m16[2] | (m16[3] << 16);
            P[2] = p16[4] | (p16[5] << 16); M[2] = m16[4] | (m16[5] << 16);
            P[3] = p16[6] | (p16[7] << 16); M[3] = m16[6] | (m16[7] << 16);
            P[4] = p16[8];                  M[4] = m16[8];
        }
        int sp = 0, sm = 0;
#pragma unroll
        for (int g = 0; g < 5; ++g) {
            sp += __builtin_popcount(P[g]);
            sm += __builtin_popcount(M[g]);
        }
#pragma unroll
        for (int o = 0; o < 23; ++o) {
            int ap = 0, am = 0;
#pragma unroll
            for (int g = 0; g < 5; ++g) {
                uint32_t Wn = wq[o * 8 + g];    // negative mask
                ap += __builtin_popcount(P[g] & Wn);
                am += __builtin_popcount(M[g] & Wn);
            }
            int s = sp - sm + 2 * (am - ap);
            plus  |= (uint32_t)(s > 0) << o;
            minus |= (uint32_t)(s < 0) << o;
        }
    }
    size_t idx = (size_t)b * H2 * STRIDE + (size_t)h * STRIDE + w;
    p2[idx] = plus;
    m2[idx] = minus;
}

// 4 px/thread ternary conv -> f32; asm bcnt chains.
__global__ __launch_bounds__(256) void k_conv3(const uint32_t* __restrict__ p2,
                                               const uint32_t* __restrict__ m2,
                                               const uint32_t* __restrict__ pw3,
                                               float* __restrict__ out) {
    int gx = blockIdx.x * 64 + threadIdx.x;   // 0..127
    int h = blockIdx.y * 4 + threadIdx.y;     // 0..507
    int b = blockIdx.z;
    int w0 = gx * 4;
    if (w0 >= H2 || h >= H3) return;
    const uint32_t* pb = p2 + (size_t)b * H2 * STRIDE;
    const uint32_t* mb = m2 + (size_t)b * H2 * STRIDE;
    uint32_t pp[3][6], mm[3][6];
#pragma unroll
    for (int r = 0; r < 3; ++r) {
        const uint32_t* rp = pb + (size_t)(h + r) * STRIDE + w0;
        uint4 q = *(const uint4*)rp;
        uint2 q2 = *(const uint2*)(rp + 4);
        pp[r][0] = q.x; pp[r][1] = q.y; pp[r][2] = q.z; pp[r][3] = q.w;
        pp[r][4] = q2.x; pp[r][5] = q2.y;
        const uint32_t* rm = mb + (size_t)(h + r) * STRIDE + w0;
        uint4 u = *(const uint4*)rm;
        uint2 u2 = *(const uint2*)(rm + 4);
        mm[r][0] = u.x; mm[r][1] = u.y; mm[r][2] = u.z; mm[r][3] = u.w;
        mm[r][4] = u2.x; mm[r][5] = u2.y;
    }
    float val[2][4];
#pragma unroll
    for (int i = 0; i < 4; ++i) {
        int Ps = 0, Ms = 0;
#pragma unroll
        for (int r = 0; r < 3; ++r)
#pragma unroll
            for (int j = 0; j < 3; ++j) {
                BCNT_ACC(Ps, pp[r][i + j]);
                BCNT_ACC(Ms, mm[r][i + j]);
            }
#pragma unroll
        for (int o = 0; o < 2; ++o) {
            int Ap = 0, Am = 0;
#pragma unroll
            for (int r = 0; r < 3; ++r)
#pragma unroll
                for (int j = 0; j < 3; ++j) {
                    uint32_t wm = pw3[o * 9 + r * 3 + j];   // uniform -> SGPR
                    uint32_t ta = pp[r][i + j] & wm;
                    uint32_t tb = mm[r][i + j] & wm;
                    BCNT_ACC(Ap, ta);
                    BCNT_ACC(Am, tb);
                }
            int s = 2 * (Ap - Am) - Ps + Ms;
            val[o][i] = (s > 0) ? 1.f : ((s < 0) ? -1.f : 0.f);
        }
    }
#pragma unroll
    for (int o = 0; o < 2; ++o) {
        float* op = out + (size_t)b * (2 * H3 * H3) + (size_t)o * (H3 * H3) + (size_t)h * H3 + w0;
        *(float2*)op = make_float2(val[o][0], val[o][1]);
        if (w0 + 3 < H3)
            *(float2*)(op + 2) = make_float2(val[o][2], val[o][3]);
    }
}

extern "C" void kernel_launch(void* const* d_in, const int* in_sizes, int n_in,
                              void* d_out, int out_size, void* d_ws, size_t ws_size,
                              hipStream_t stream) {
    const float* inputs = (const float*)d_in[0];
    const float* w1 = (const float*)d_in[1];
    const float* w2 = (const float*)d_in[2];
    const float* w3 = (const float*)d_in[3];
    float* out = (float*)d_out;
    char* ws = (char*)d_ws;

    float* lw = (float*)(ws + 0);             // 448 f32 (reordered sign(w1))
    uint32_t* pw2 = (uint32_t*)(ws + 2048);   // 184 u32 (neg masks, stride 8/o)
    uint32_t* pw3 = (uint32_t*)(ws + 4096);   // 18 u32
    uint32_t* t1 = (uint32_t*)(ws + 8192);    // 32*510*512 u32 (L1: n | z<<16)
    size_t off_p2 = 8192 + (size_t)32 * H1 * STRIDE * 4;
    uint32_t* p2 = (uint32_t*)(ws + off_p2);  // 32*508*512 u32
    size_t off_m2 = off_p2 + (size_t)32 * H2 * STRIDE * 4;
    uint32_t* m2 = (uint32_t*)(ws + off_m2);
    size_t need = off_m2 + (size_t)32 * H2 * STRIDE * 4;
    if (ws_size < need) return;

    hipLaunchKernelGGL(k_prep, dim3(1), dim3(256), 0, stream, w1, w2, w3, lw, pw2, pw3);
    hipLaunchKernelGGL(k_conv1, dim3(2, 64, 32), dim3(64, 4), 0, stream, inputs, lw, t1);
    hipLaunchKernelGGL(k_conv2, dim3(8, 127, 32), dim3(64, 4), 0, stream, t1, pw2, p2, m2);
    hipLaunchKernelGGL(k_conv3, dim3(2, 127, 32), dim3(64, 4), 0, stream, p2, m2, pw3, out);
}